// Round 9
// baseline (3260.532 us; speedup 1.0000x reference)
//
#include <hip/hip_runtime.h>
#include <math.h>

constexpr int NN   = 100000;   // nodes
constexpr int DIM  = 128;
constexpr int NE   = 3200000;  // edges
constexpr int NCLS = 40;
constexpr float EPSF = 1e-7f;

constexpr int BSH  = 9;                      // 512 cols per coarse bucket
constexpr int BSZ  = 1 << BSH;
constexpr int NBKT = (NN + BSZ - 1) >> BSH;  // 196
constexpr int CAP  = 18432;                  // bucket capacity
constexpr int AEPB = 4096;                   // edges per binA block
constexpr int ABLK = (NE + AEPB - 1) / AEPB; // 782

constexpr int QS   = 4;                      // class quarters in h_kernel
constexpr int QCLS = NCLS / QS;              // 10
constexpr int HNB  = 128;                    // nodes per h block
constexpr int HT   = 512;                    // h threads
constexpr int KC   = 32;                     // k-chunk
constexpr int TP   = 33;                     // tile row pad (conflict-free b32)

// ---- pass A: coarse-bucket partition with LDS shuffle, coalesced run writes
__global__ __launch_bounds__(256) void binA_kernel(const int* __restrict__ row,
                                                   const int* __restrict__ col,
                                                   int* __restrict__ gcur,
                                                   unsigned* __restrict__ pairs) {
    __shared__ int hist[256];
    __shared__ int lofx[256];
    __shared__ int gbase[256];
    __shared__ unsigned sortedw[AEPB];
    __shared__ int dstg[AEPB];

    int t = threadIdx.x;
    int e0 = blockIdx.x * AEPB;
    int cnt = min(AEPB, NE - e0);

    hist[t] = 0;
    __syncthreads();
    for (int k = t; k < cnt; k += 256) atomicAdd(&hist[col[e0 + k] >> BSH], 1);
    __syncthreads();

    int h = hist[t];
    if (t < NBKT && h > 0) gbase[t] = atomicAdd(&gcur[t], h);
    lofx[t] = h;
    __syncthreads();
    for (int d = 1; d < 256; d <<= 1) {
        int o = (t >= d) ? lofx[t - d] : 0;
        __syncthreads();
        lofx[t] += o;
        __syncthreads();
    }
    int excl = lofx[t] - h;
    lofx[t] = excl;
    hist[t] = excl;
    __syncthreads();

    for (int k = t; k < cnt; k += 256) {
        int c = col[e0 + k], r = row[e0 + k];
        int b = c >> BSH;
        int pos = atomicAdd(&hist[b], 1);
        sortedw[pos] = ((unsigned)(c & (BSZ - 1)) << 17) | (unsigned)r;
        dstg[pos] = b * CAP + gbase[b] + (pos - lofx[b]);
    }
    __syncthreads();
    for (int k = t; k < cnt; k += 256) pairs[dstg[k]] = sortedw[k];
}

// ---- bucket-base exclusive scan (196 values, one block) --------------------
__global__ __launch_bounds__(256) void bscan_kernel(const int* __restrict__ gcur,
                                                    int* __restrict__ bbase) {
    __shared__ int sc[256];
    int t = threadIdx.x;
    int v = (t < NBKT) ? gcur[t] : 0;
    sc[t] = v;
    __syncthreads();
    for (int d = 1; d < 256; d <<= 1) {
        int o = (t >= d) ? sc[t - d] : 0;
        __syncthreads();
        sc[t] += o;
        __syncthreads();
    }
    if (t < NBKT) bbase[t] = sc[t] - v;
}

// ---- pass B: per-bucket counting sort in LDS; writes offs + coalesced ebuf -
__global__ __launch_bounds__(1024) void binB_kernel(const int* __restrict__ gcur,
                                                    const int* __restrict__ bbase,
                                                    const unsigned* __restrict__ pairs,
                                                    int* __restrict__ ebuf,
                                                    int* __restrict__ offs) {
    __shared__ unsigned in[CAP];
    __shared__ int srow[CAP];
    __shared__ int hist[512];
    __shared__ int sc[1024];

    int t = threadIdx.x;
    int b = blockIdx.x;
    int cnt = gcur[b];
    int base = bbase[b];
    const unsigned* pb = pairs + (size_t)b * CAP;

    for (int i = t; i < cnt; i += 1024) in[i] = pb[i];
    if (t < 512) hist[t] = 0;
    __syncthreads();
    for (int i = t; i < cnt; i += 1024) atomicAdd(&hist[in[i] >> 17], 1);
    __syncthreads();

    int v = (t < 512) ? hist[t] : 0;
    sc[t] = v;
    __syncthreads();
    for (int d = 1; d < 1024; d <<= 1) {
        int o = (t >= d) ? sc[t - d] : 0;
        __syncthreads();
        sc[t] += o;
        __syncthreads();
    }
    int excl = sc[t] - v;
    if (t < 512) {
        int c = (b << BSH) + t;
        if (c <= NN) offs[c] = base + excl;
        hist[t] = excl;
    }
    __syncthreads();
    for (int i = t; i < cnt; i += 1024) {
        unsigned w = in[i];
        int pos = atomicAdd(&hist[w >> 17], 1);
        srow[pos] = (int)(w & 0x1FFFFu);
    }
    __syncthreads();
    for (int i = t; i < cnt; i += 1024) ebuf[base + i] = srow[i];
}

// ---------------- h = concat(xE, logH, logS) @ W ; g = h * dinv -------------
// 512 thr / 128 nodes / 4 quarters. W fully in LDS (broadcast). x staged in
// coalesced 32-k LDS chunks (pad 33 -> conflict-free b32 reads). 3 acc sets;
// logmap scales applied at the end (x0 stashed at stage time, slot zeroed).
__global__ __launch_bounds__(HT) void h_kernel(
    const float* __restrict__ xE, const float* __restrict__ xH,
    const float* __restrict__ xS, const float* __restrict__ W,
    const int* __restrict__ offs, float* __restrict__ g) {

    __shared__ float Wl[3 * DIM * NCLS];   // 61440 B
    __shared__ float tile[HNB * TP];       // 16896 B
    __shared__ float x0H[HNB], x0S[HNB];   // 1024 B

    int t = threadIdx.x;
    int n0 = blockIdx.x * HNB;

    {
        const float4* W4 = reinterpret_cast<const float4*>(W);
        float4* Wl4 = reinterpret_cast<float4*>(Wl);
        for (int i = t; i < 3 * DIM * NCLS / 4; i += HT) Wl4[i] = W4[i];
    }

    int q  = t >> 7;        // wave-uniform (wave = t>>6, q = wave>>1)
    int nl = t & (HNB - 1);

    float accE[QCLS], accH[QCLS], accS[QCLS];
#pragma unroll
    for (int c = 0; c < QCLS; ++c) { accE[c] = 0.f; accH[c] = 0.f; accS[c] = 0.f; }

    const float* trow = &tile[nl * TP];

    auto do_manifold = [&](const float* __restrict__ xbase,
                           float* __restrict__ acc, int m) {
#pragma unroll
        for (int kc = 0; kc < DIM / KC; ++kc) {
            __syncthreads();   // protect previous tile use (and W load, 1st time)
#pragma unroll
            for (int p = 0; p < 2; ++p) {
                int f4i = p * HT + t;           // 0..1023
                int row = f4i >> 3;
                int kq  = f4i & 7;
                int gr  = n0 + row;
                float4 v = make_float4(0.f, 0.f, 0.f, 0.f);
                if (gr < NN)
                    v = *reinterpret_cast<const float4*>(
                        xbase + (size_t)gr * DIM + kc * KC + kq * 4);
                if (m > 0 && kc == 0 && kq == 0) {
                    if (m == 1) x0H[row] = v.x; else x0S[row] = v.x;
                    v.x = 0.f;
                }
                float* d = &tile[row * TP + kq * 4];
                d[0] = v.x; d[1] = v.y; d[2] = v.z; d[3] = v.w;
            }
            __syncthreads();
            const float* wb = &Wl[(m * DIM + kc * KC) * NCLS + q * QCLS];
#pragma unroll
            for (int k = 0; k < KC; ++k) {
                float xk = trow[k];
#pragma unroll
                for (int c = 0; c < QCLS; ++c)
                    acc[c] = fmaf(xk, wb[k * NCLS + c], acc[c]);
            }
        }
    };

    do_manifold(xE, accE, 0);
    do_manifold(xH, accH, 1);
    do_manifold(xS, accS, 2);

    int n = n0 + nl;
    if (n >= NN) return;

    float h0 = x0H[nl];
    float sH = acoshf(fmaxf(h0, 1.f)) * rsqrtf(fmaxf(h0 * h0 - 1.f, EPSF));
    float s0 = x0S[nl];
    float cc = fminf(fmaxf(s0, -1.f), 1.f);
    float sS = acosf(cc) * rsqrtf(fmaxf(1.f - s0 * s0, EPSF));
    float dinv = rsqrtf((float)(offs[n + 1] - offs[n] + 1));  // +1 self loop

    float* gn = g + (size_t)n * NCLS + q * QCLS;
#pragma unroll
    for (int c2 = 0; c2 < QCLS / 2; ++c2) {
        float a = (accE[c2 * 2]     + sH * accH[c2 * 2]     + sS * accS[c2 * 2]) * dinv;
        float b = (accE[c2 * 2 + 1] + sH * accH[c2 * 2 + 1] + sS * accS[c2 * 2 + 1]) * dinv;
        *reinterpret_cast<float2*>(gn + c2 * 2) = make_float2(a, b);
    }
}

// ------ gather: float4 per thread (10 threads/node), 4x unrolled edge loop ---
__global__ __launch_bounds__(256) void gather_kernel(
    const int* __restrict__ offs, const int* __restrict__ ebuf,
    const float* __restrict__ g, float* __restrict__ out) {
    int t = blockIdx.x * blockDim.x + threadIdx.x;
    if (t >= NN * (NCLS / 4)) return;
    int n  = t / (NCLS / 4);
    int c4 = t - n * (NCLS / 4);

    int s = offs[n], e = offs[n + 1];
    float dinv = rsqrtf((float)(e - s + 1));
    const float4* g4 = reinterpret_cast<const float4*>(g);
    float4 a = g4[n * (NCLS / 4) + c4];      // self loop (dinv[n] folded in g)
    float ax = a.x, ay = a.y, az = a.z, aw = a.w;
    float bx = 0.f, by = 0.f, bz = 0.f, bw = 0.f;
    float cx = 0.f, cy = 0.f, cz = 0.f, cw = 0.f;
    float dx = 0.f, dy = 0.f, dz = 0.f, dw = 0.f;
    int j = s;
    for (; j + 3 < e; j += 4) {
        int r0 = ebuf[j], r1 = ebuf[j + 1], r2 = ebuf[j + 2], r3 = ebuf[j + 3];
        float4 v0 = g4[r0 * (NCLS / 4) + c4];
        float4 v1 = g4[r1 * (NCLS / 4) + c4];
        float4 v2 = g4[r2 * (NCLS / 4) + c4];
        float4 v3 = g4[r3 * (NCLS / 4) + c4];
        ax += v0.x; ay += v0.y; az += v0.z; aw += v0.w;
        bx += v1.x; by += v1.y; bz += v1.z; bw += v1.w;
        cx += v2.x; cy += v2.y; cz += v2.z; cw += v2.w;
        dx += v3.x; dy += v3.y; dz += v3.z; dw += v3.w;
    }
    for (; j < e; ++j) {
        float4 v = g4[ebuf[j] * (NCLS / 4) + c4];
        ax += v.x; ay += v.y; az += v.z; aw += v.w;
    }
    float4 o;
    o.x = (ax + bx + cx + dx) * dinv;
    o.y = (ay + by + cy + dy) * dinv;
    o.z = (az + bz + cz + dz) * dinv;
    o.w = (aw + bw + cw + dw) * dinv;
    reinterpret_cast<float4*>(out)[t] = o;
}

extern "C" void kernel_launch(void* const* d_in, const int* in_sizes, int n_in,
                              void* d_out, int out_size, void* d_ws, size_t ws_size,
                              hipStream_t stream) {
    const float* xE = (const float*)d_in[0];
    const float* xH = (const float*)d_in[1];
    const float* xS = (const float*)d_in[2];
    const float* W  = (const float*)d_in[3];
    const int*   ei = (const int*)d_in[4];
    const int* row = ei;            // edge_index[0]
    const int* col = ei + NE;       // edge_index[1]
    float* out = (float*)d_out;

    auto pad = [](size_t x) { return (x + 255) & ~(size_t)255; };
    char* p = (char*)d_ws;
    int* gcur  = (int*)p;               p += pad((size_t)NBKT * 4);
    int* bbase = (int*)p;               p += pad((size_t)NBKT * 4);
    int* offs  = (int*)p;               p += pad((size_t)(NN + 1) * 4);
    int* ebuf  = (int*)p;               p += pad((size_t)NE * 4);
    float* g   = (float*)p;             // NN*NCLS floats (16 MB)
    unsigned* pairs = (unsigned*)g;     // aliases g: pairs dead before h writes g

    hipMemsetAsync(gcur, 0, (size_t)NBKT * 4, stream);

    binA_kernel<<<ABLK, 256, 0, stream>>>(row, col, gcur, pairs);
    bscan_kernel<<<1, 256, 0, stream>>>(gcur, bbase);
    binB_kernel<<<NBKT, 1024, 0, stream>>>(gcur, bbase, pairs, ebuf, offs);
    h_kernel<<<(NN + HNB - 1) / HNB, HT, 0, stream>>>(xE, xH, xS, W, offs, g);
    gather_kernel<<<(NN * (NCLS / 4) + 255) / 256, 256, 0, stream>>>(offs, ebuf, g, out);
}

// Round 10
// 3158.507 us; speedup vs baseline: 1.0323x; 1.0323x over previous
//
#include <hip/hip_runtime.h>
#include <math.h>

constexpr int NN   = 100000;   // nodes
constexpr int DIM  = 128;
constexpr int NE   = 3200000;  // edges
constexpr int NCLS = 40;
constexpr float EPSF = 1e-7f;

constexpr int BSH  = 9;                      // 512 cols per coarse bucket
constexpr int BSZ  = 1 << BSH;
constexpr int NBKT = (NN + BSZ - 1) >> BSH;  // 196
constexpr int CAP  = 18432;                  // bucket capacity
constexpr int AEPB = 4096;                   // edges per binA block
constexpr int ABLK = (NE + AEPB - 1) / AEPB; // 782

constexpr int QS   = 4;                      // class quarters in h_kernel
constexpr int QCLS = NCLS / QS;              // 10
constexpr int HNB  = 128;                    // nodes per h block
constexpr int HT   = 512;                    // h threads
constexpr int KC   = 32;                     // k-chunk
constexpr int TP   = 33;                     // tile row pad (conflict-free b32)

// ---- pass A: coarse-bucket partition with LDS shuffle, coalesced run writes
__global__ __launch_bounds__(256) void binA_kernel(const int* __restrict__ row,
                                                   const int* __restrict__ col,
                                                   int* __restrict__ gcur,
                                                   unsigned* __restrict__ pairs) {
    __shared__ int hist[256];
    __shared__ int lofx[256];
    __shared__ int gbase[256];
    __shared__ unsigned sortedw[AEPB];
    __shared__ int dstg[AEPB];

    int t = threadIdx.x;
    int e0 = blockIdx.x * AEPB;
    int cnt = min(AEPB, NE - e0);

    hist[t] = 0;
    __syncthreads();
    for (int k = t; k < cnt; k += 256) atomicAdd(&hist[col[e0 + k] >> BSH], 1);
    __syncthreads();

    int h = hist[t];
    if (t < NBKT && h > 0) gbase[t] = atomicAdd(&gcur[t], h);
    lofx[t] = h;
    __syncthreads();
    for (int d = 1; d < 256; d <<= 1) {
        int o = (t >= d) ? lofx[t - d] : 0;
        __syncthreads();
        lofx[t] += o;
        __syncthreads();
    }
    int excl = lofx[t] - h;
    lofx[t] = excl;
    hist[t] = excl;
    __syncthreads();

    for (int k = t; k < cnt; k += 256) {
        int c = col[e0 + k], r = row[e0 + k];
        int b = c >> BSH;
        int pos = atomicAdd(&hist[b], 1);
        sortedw[pos] = ((unsigned)(c & (BSZ - 1)) << 17) | (unsigned)r;
        dstg[pos] = b * CAP + gbase[b] + (pos - lofx[b]);
    }
    __syncthreads();
    for (int k = t; k < cnt; k += 256) pairs[dstg[k]] = sortedw[k];
}

// ---- bucket-base exclusive scan (196 values, one block) --------------------
__global__ __launch_bounds__(256) void bscan_kernel(const int* __restrict__ gcur,
                                                    int* __restrict__ bbase) {
    __shared__ int sc[256];
    int t = threadIdx.x;
    int v = (t < NBKT) ? gcur[t] : 0;
    sc[t] = v;
    __syncthreads();
    for (int d = 1; d < 256; d <<= 1) {
        int o = (t >= d) ? sc[t - d] : 0;
        __syncthreads();
        sc[t] += o;
        __syncthreads();
    }
    if (t < NBKT) bbase[t] = sc[t] - v;
}

// ---- pass B: per-bucket counting sort in LDS; writes offs + coalesced ebuf -
__global__ __launch_bounds__(1024) void binB_kernel(const int* __restrict__ gcur,
                                                    const int* __restrict__ bbase,
                                                    const unsigned* __restrict__ pairs,
                                                    int* __restrict__ ebuf,
                                                    int* __restrict__ offs) {
    __shared__ unsigned in[CAP];
    __shared__ int srow[CAP];
    __shared__ int hist[512];
    __shared__ int sc[1024];

    int t = threadIdx.x;
    int b = blockIdx.x;
    int cnt = gcur[b];
    int base = bbase[b];
    const unsigned* pb = pairs + (size_t)b * CAP;

    for (int i = t; i < cnt; i += 1024) in[i] = pb[i];
    if (t < 512) hist[t] = 0;
    __syncthreads();
    for (int i = t; i < cnt; i += 1024) atomicAdd(&hist[in[i] >> 17], 1);
    __syncthreads();

    int v = (t < 512) ? hist[t] : 0;
    sc[t] = v;
    __syncthreads();
    for (int d = 1; d < 1024; d <<= 1) {
        int o = (t >= d) ? sc[t - d] : 0;
        __syncthreads();
        sc[t] += o;
        __syncthreads();
    }
    int excl = sc[t] - v;
    if (t < 512) {
        int c = (b << BSH) + t;
        if (c <= NN) offs[c] = base + excl;
        hist[t] = excl;
    }
    __syncthreads();
    for (int i = t; i < cnt; i += 1024) {
        unsigned w = in[i];
        int pos = atomicAdd(&hist[w >> 17], 1);
        srow[pos] = (int)(w & 0x1FFFFu);
    }
    __syncthreads();
    for (int i = t; i < cnt; i += 1024) ebuf[base + i] = srow[i];
}

// ---------------- h = concat(xE, logH, logS) @ W ; g = h * dinv -------------
// 512 thr / 128 nodes / 4 quarters. W in LDS (broadcast); x staged in
// coalesced 32-k LDS chunks. SINGLE acc[10], constant indices only (no
// address-taking -> stays in VGPRs). Manifold scale folded into the MAC
// operand; scale computed from stashed x0 right after the kc=0 stage.
__global__ __launch_bounds__(HT) void h_kernel(
    const float* __restrict__ xE, const float* __restrict__ xH,
    const float* __restrict__ xS, const float* __restrict__ W,
    const int* __restrict__ offs, float* __restrict__ g) {

    __shared__ float Wl[3 * DIM * NCLS];   // 61440 B
    __shared__ float tile[HNB * TP];       // 16896 B
    __shared__ float x0s[HNB];             // 512 B
    __shared__ float scs[HNB];             // 512 B

    int t = threadIdx.x;
    int n0 = blockIdx.x * HNB;

    {
        const float4* W4 = reinterpret_cast<const float4*>(W);
        float4* Wl4 = reinterpret_cast<float4*>(Wl);
        for (int i = t; i < 3 * DIM * NCLS / 4; i += HT) Wl4[i] = W4[i];
    }

    int q  = t >> 7;        // wave-uniform quarter id
    int nl = t & (HNB - 1);

    float acc[QCLS];
#pragma unroll
    for (int c = 0; c < QCLS; ++c) acc[c] = 0.f;

    const float* trow = &tile[nl * TP];

#pragma unroll
    for (int m = 0; m < 3; ++m) {
        const float* xbase = (m == 0) ? xE : (m == 1) ? xH : xS;
#pragma unroll
        for (int kc = 0; kc < DIM / KC; ++kc) {
            __syncthreads();   // protect previous tile use (and W load, 1st time)
#pragma unroll
            for (int p = 0; p < 2; ++p) {
                int f4i = p * HT + t;           // 0..1023
                int rowi = f4i >> 3;
                int kq   = f4i & 7;
                int gr   = n0 + rowi;
                float4 v = make_float4(0.f, 0.f, 0.f, 0.f);
                if (gr < NN)
                    v = *reinterpret_cast<const float4*>(
                        xbase + (size_t)gr * DIM + kc * KC + kq * 4);
                if (m > 0 && kc == 0 && kq == 0) {
                    x0s[rowi] = v.x;
                    v.x = 0.f;
                }
                float* d = &tile[rowi * TP + kq * 4];
                d[0] = v.x; d[1] = v.y; d[2] = v.z; d[3] = v.w;
            }
            __syncthreads();
            if (m > 0 && kc == 0) {
                if (t < HNB) {
                    float x0 = x0s[t];
                    float sc;
                    if (m == 1) {
                        sc = acoshf(fmaxf(x0, 1.f)) *
                             rsqrtf(fmaxf(x0 * x0 - 1.f, EPSF));
                    } else {
                        float cc = fminf(fmaxf(x0, -1.f), 1.f);
                        sc = acosf(cc) * rsqrtf(fmaxf(1.f - x0 * x0, EPSF));
                    }
                    scs[t] = sc;
                }
                __syncthreads();
            }
            float scm = (m == 0) ? 1.f : scs[nl];
            const float* wb = &Wl[(m * DIM + kc * KC) * NCLS + q * QCLS];
#pragma unroll
            for (int k = 0; k < KC; ++k) {
                float xk = trow[k] * scm;
#pragma unroll
                for (int c = 0; c < QCLS; ++c)
                    acc[c] = fmaf(xk, wb[k * NCLS + c], acc[c]);
            }
        }
    }

    int n = n0 + nl;
    if (n >= NN) return;

    float dinv = rsqrtf((float)(offs[n + 1] - offs[n] + 1));  // +1 self loop
    float* gn = g + (size_t)n * NCLS + q * QCLS;
#pragma unroll
    for (int c2 = 0; c2 < QCLS / 2; ++c2) {
        float a = acc[c2 * 2] * dinv;
        float b = acc[c2 * 2 + 1] * dinv;
        *reinterpret_cast<float2*>(gn + c2 * 2) = make_float2(a, b);
    }
}

// ------ gather: float4 per thread (10 threads/node), 4x unrolled edge loop ---
__global__ __launch_bounds__(256) void gather_kernel(
    const int* __restrict__ offs, const int* __restrict__ ebuf,
    const float* __restrict__ g, float* __restrict__ out) {
    int t = blockIdx.x * blockDim.x + threadIdx.x;
    if (t >= NN * (NCLS / 4)) return;
    int n  = t / (NCLS / 4);
    int c4 = t - n * (NCLS / 4);

    int s = offs[n], e = offs[n + 1];
    float dinv = rsqrtf((float)(e - s + 1));
    const float4* g4 = reinterpret_cast<const float4*>(g);
    float4 a = g4[n * (NCLS / 4) + c4];      // self loop (dinv[n] folded in g)
    float ax = a.x, ay = a.y, az = a.z, aw = a.w;
    float bx = 0.f, by = 0.f, bz = 0.f, bw = 0.f;
    float cx = 0.f, cy = 0.f, cz = 0.f, cw = 0.f;
    float dx = 0.f, dy = 0.f, dz = 0.f, dw = 0.f;
    int j = s;
    for (; j + 3 < e; j += 4) {
        int r0 = ebuf[j], r1 = ebuf[j + 1], r2 = ebuf[j + 2], r3 = ebuf[j + 3];
        float4 v0 = g4[r0 * (NCLS / 4) + c4];
        float4 v1 = g4[r1 * (NCLS / 4) + c4];
        float4 v2 = g4[r2 * (NCLS / 4) + c4];
        float4 v3 = g4[r3 * (NCLS / 4) + c4];
        ax += v0.x; ay += v0.y; az += v0.z; aw += v0.w;
        bx += v1.x; by += v1.y; bz += v1.z; bw += v1.w;
        cx += v2.x; cy += v2.y; cz += v2.z; cw += v2.w;
        dx += v3.x; dy += v3.y; dz += v3.z; dw += v3.w;
    }
    for (; j < e; ++j) {
        float4 v = g4[ebuf[j] * (NCLS / 4) + c4];
        ax += v.x; ay += v.y; az += v.z; aw += v.w;
    }
    float4 o;
    o.x = (ax + bx + cx + dx) * dinv;
    o.y = (ay + by + cy + dy) * dinv;
    o.z = (az + bz + cz + dz) * dinv;
    o.w = (aw + bw + cw + dw) * dinv;
    reinterpret_cast<float4*>(out)[t] = o;
}

extern "C" void kernel_launch(void* const* d_in, const int* in_sizes, int n_in,
                              void* d_out, int out_size, void* d_ws, size_t ws_size,
                              hipStream_t stream) {
    const float* xE = (const float*)d_in[0];
    const float* xH = (const float*)d_in[1];
    const float* xS = (const float*)d_in[2];
    const float* W  = (const float*)d_in[3];
    const int*   ei = (const int*)d_in[4];
    const int* row = ei;            // edge_index[0]
    const int* col = ei + NE;       // edge_index[1]
    float* out = (float*)d_out;

    auto pad = [](size_t x) { return (x + 255) & ~(size_t)255; };
    char* p = (char*)d_ws;
    int* gcur  = (int*)p;               p += pad((size_t)NBKT * 4);
    int* bbase = (int*)p;               p += pad((size_t)NBKT * 4);
    int* offs  = (int*)p;               p += pad((size_t)(NN + 1) * 4);
    int* ebuf  = (int*)p;               p += pad((size_t)NE * 4);
    float* g   = (float*)p;             // NN*NCLS floats (16 MB)
    unsigned* pairs = (unsigned*)g;     // aliases g: pairs dead before h writes g

    hipMemsetAsync(gcur, 0, (size_t)NBKT * 4, stream);

    binA_kernel<<<ABLK, 256, 0, stream>>>(row, col, gcur, pairs);
    bscan_kernel<<<1, 256, 0, stream>>>(gcur, bbase);
    binB_kernel<<<NBKT, 1024, 0, stream>>>(gcur, bbase, pairs, ebuf, offs);
    h_kernel<<<(NN + HNB - 1) / HNB, HT, 0, stream>>>(xE, xH, xS, W, offs, g);
    gather_kernel<<<(NN * (NCLS / 4) + 255) / 256, 256, 0, stream>>>(offs, ebuf, g, out);
}

// Round 11
// 348.572 us; speedup vs baseline: 9.3540x; 9.0613x over previous
//
#include <hip/hip_runtime.h>
#include <math.h>

constexpr int NN   = 100000;   // nodes
constexpr int DIM  = 128;
constexpr int NE   = 3200000;  // edges
constexpr int NCLS = 40;
constexpr float EPSF = 1e-7f;

constexpr int BSH  = 9;                      // 512 cols per coarse bucket
constexpr int BSZ  = 1 << BSH;
constexpr int NBKT = (NN + BSZ - 1) >> BSH;  // 196
constexpr int CAP  = 18432;                  // bucket capacity
constexpr int AEPB = 4096;                   // edges per binA block
constexpr int ABLK = (NE + AEPB - 1) / AEPB; // 782

constexpr int QS   = 4;                      // class quarters in h_kernel
constexpr int QCLS = NCLS / QS;              // 10
constexpr int HNB  = 128;                    // nodes per h block
constexpr int HT   = 512;                    // h threads
constexpr int KC   = 32;                     // k-chunk
constexpr int TP   = 33;                     // tile row pad (conflict-free b32)

// ---- pass A: coarse-bucket partition with LDS shuffle, coalesced run writes
__global__ __launch_bounds__(256) void binA_kernel(const int* __restrict__ row,
                                                   const int* __restrict__ col,
                                                   int* __restrict__ gcur,
                                                   unsigned* __restrict__ pairs) {
    __shared__ int hist[256];
    __shared__ int lofx[256];
    __shared__ int gbase[256];
    __shared__ unsigned sortedw[AEPB];
    __shared__ int dstg[AEPB];

    int t = threadIdx.x;
    int e0 = blockIdx.x * AEPB;
    int cnt = min(AEPB, NE - e0);

    hist[t] = 0;
    __syncthreads();
    for (int k = t; k < cnt; k += 256) atomicAdd(&hist[col[e0 + k] >> BSH], 1);
    __syncthreads();

    int h = hist[t];
    if (t < NBKT && h > 0) gbase[t] = atomicAdd(&gcur[t], h);
    lofx[t] = h;
    __syncthreads();
    for (int d = 1; d < 256; d <<= 1) {
        int o = (t >= d) ? lofx[t - d] : 0;
        __syncthreads();
        lofx[t] += o;
        __syncthreads();
    }
    int excl = lofx[t] - h;
    lofx[t] = excl;
    hist[t] = excl;
    __syncthreads();

    for (int k = t; k < cnt; k += 256) {
        int c = col[e0 + k], r = row[e0 + k];
        int b = c >> BSH;
        int pos = atomicAdd(&hist[b], 1);
        sortedw[pos] = ((unsigned)(c & (BSZ - 1)) << 17) | (unsigned)r;
        dstg[pos] = b * CAP + gbase[b] + (pos - lofx[b]);
    }
    __syncthreads();
    for (int k = t; k < cnt; k += 256) pairs[dstg[k]] = sortedw[k];
}

// ---- bucket-base exclusive scan (196 values, one block) --------------------
__global__ __launch_bounds__(256) void bscan_kernel(const int* __restrict__ gcur,
                                                    int* __restrict__ bbase) {
    __shared__ int sc[256];
    int t = threadIdx.x;
    int v = (t < NBKT) ? gcur[t] : 0;
    sc[t] = v;
    __syncthreads();
    for (int d = 1; d < 256; d <<= 1) {
        int o = (t >= d) ? sc[t - d] : 0;
        __syncthreads();
        sc[t] += o;
        __syncthreads();
    }
    if (t < NBKT) bbase[t] = sc[t] - v;
}

// ---- pass B: per-bucket counting sort in LDS; writes offs + coalesced ebuf -
__global__ __launch_bounds__(1024) void binB_kernel(const int* __restrict__ gcur,
                                                    const int* __restrict__ bbase,
                                                    const unsigned* __restrict__ pairs,
                                                    int* __restrict__ ebuf,
                                                    int* __restrict__ offs) {
    __shared__ unsigned in[CAP];
    __shared__ int srow[CAP];
    __shared__ int hist[512];
    __shared__ int sc[1024];

    int t = threadIdx.x;
    int b = blockIdx.x;
    int cnt = gcur[b];
    int base = bbase[b];
    const unsigned* pb = pairs + (size_t)b * CAP;

    for (int i = t; i < cnt; i += 1024) in[i] = pb[i];
    if (t < 512) hist[t] = 0;
    __syncthreads();
    for (int i = t; i < cnt; i += 1024) atomicAdd(&hist[in[i] >> 17], 1);
    __syncthreads();

    int v = (t < 512) ? hist[t] : 0;
    sc[t] = v;
    __syncthreads();
    for (int d = 1; d < 1024; d <<= 1) {
        int o = (t >= d) ? sc[t - d] : 0;
        __syncthreads();
        sc[t] += o;
        __syncthreads();
    }
    int excl = sc[t] - v;
    if (t < 512) {
        int c = (b << BSH) + t;
        if (c <= NN) offs[c] = base + excl;
        hist[t] = excl;
    }
    __syncthreads();
    for (int i = t; i < cnt; i += 1024) {
        unsigned w = in[i];
        int pos = atomicAdd(&hist[w >> 17], 1);
        srow[pos] = (int)(w & 0x1FFFFu);
    }
    __syncthreads();
    for (int i = t; i < cnt; i += 1024) ebuf[base + i] = srow[i];
}

// ---------------- h = concat(xE, logH, logS) @ W ; g = h * dinv -------------
// x staged in LDS (coalesced, conflict-free). W from GLOBAL via wave-uniform
// scalar loads (q = readfirstlane -> s_load through constant cache; the R8
// path that gave VGPR=20). LDS W staging caused the R9/R10 spill -> removed.
__global__ __launch_bounds__(HT) void h_kernel(
    const float* __restrict__ xE, const float* __restrict__ xH,
    const float* __restrict__ xS, const float* __restrict__ W,
    const int* __restrict__ offs, float* __restrict__ g) {

    __shared__ float tile[HNB * TP];       // 16896 B
    __shared__ float x0s[HNB];             // 512 B
    __shared__ float scs[HNB];             // 512 B

    int t = threadIdx.x;
    int n0 = blockIdx.x * HNB;
    int q  = __builtin_amdgcn_readfirstlane(t >> 7);   // wave-uniform quarter
    int nl = t & (HNB - 1);

    float acc[QCLS];
#pragma unroll
    for (int c = 0; c < QCLS; ++c) acc[c] = 0.f;

    const float* trow = &tile[nl * TP];

    for (int m = 0; m < 3; ++m) {
        const float* xbase = (m == 0) ? xE : (m == 1) ? xH : xS;
#pragma unroll
        for (int kc = 0; kc < DIM / KC; ++kc) {
            __syncthreads();   // protect previous tile use
#pragma unroll
            for (int p = 0; p < 2; ++p) {
                int f4i = p * HT + t;           // 0..1023
                int rowi = f4i >> 3;
                int kq   = f4i & 7;
                int gr   = n0 + rowi;
                float4 v = make_float4(0.f, 0.f, 0.f, 0.f);
                if (gr < NN)
                    v = *reinterpret_cast<const float4*>(
                        xbase + (size_t)gr * DIM + kc * KC + kq * 4);
                if (m > 0 && kc == 0 && kq == 0) {
                    x0s[rowi] = v.x;
                    v.x = 0.f;
                }
                float* d = &tile[rowi * TP + kq * 4];
                d[0] = v.x; d[1] = v.y; d[2] = v.z; d[3] = v.w;
            }
            __syncthreads();
            if (m > 0 && kc == 0) {
                if (t < HNB) {
                    float x0 = x0s[t];
                    float sc;
                    if (m == 1) {
                        sc = acoshf(fmaxf(x0, 1.f)) *
                             rsqrtf(fmaxf(x0 * x0 - 1.f, EPSF));
                    } else {
                        float cc = fminf(fmaxf(x0, -1.f), 1.f);
                        sc = acosf(cc) * rsqrtf(fmaxf(1.f - x0 * x0, EPSF));
                    }
                    scs[t] = sc;
                }
                __syncthreads();
            }
            float scm = (m == 0) ? 1.f : scs[nl];
            const float* wb = W + (size_t)(m * DIM + kc * KC) * NCLS + q * QCLS;
#pragma unroll
            for (int k = 0; k < KC; ++k) {
                float xk = trow[k] * scm;
#pragma unroll
                for (int c = 0; c < QCLS; ++c)
                    acc[c] = fmaf(xk, wb[k * NCLS + c], acc[c]);
            }
        }
    }

    int n = n0 + nl;
    if (n >= NN) return;

    float dinv = rsqrtf((float)(offs[n + 1] - offs[n] + 1));  // +1 self loop
    float* gn = g + (size_t)n * NCLS + q * QCLS;
#pragma unroll
    for (int c2 = 0; c2 < QCLS / 2; ++c2) {
        float a = acc[c2 * 2] * dinv;
        float b = acc[c2 * 2 + 1] * dinv;
        *reinterpret_cast<float2*>(gn + c2 * 2) = make_float2(a, b);
    }
}

// ------ gather: float4 per thread (10 threads/node), 4x unrolled edge loop ---
__global__ __launch_bounds__(256) void gather_kernel(
    const int* __restrict__ offs, const int* __restrict__ ebuf,
    const float* __restrict__ g, float* __restrict__ out) {
    int t = blockIdx.x * blockDim.x + threadIdx.x;
    if (t >= NN * (NCLS / 4)) return;
    int n  = t / (NCLS / 4);
    int c4 = t - n * (NCLS / 4);

    int s = offs[n], e = offs[n + 1];
    float dinv = rsqrtf((float)(e - s + 1));
    const float4* g4 = reinterpret_cast<const float4*>(g);
    float4 a = g4[n * (NCLS / 4) + c4];      // self loop (dinv[n] folded in g)
    float ax = a.x, ay = a.y, az = a.z, aw = a.w;
    float bx = 0.f, by = 0.f, bz = 0.f, bw = 0.f;
    float cx = 0.f, cy = 0.f, cz = 0.f, cw = 0.f;
    float dx = 0.f, dy = 0.f, dz = 0.f, dw = 0.f;
    int j = s;
    for (; j + 3 < e; j += 4) {
        int r0 = ebuf[j], r1 = ebuf[j + 1], r2 = ebuf[j + 2], r3 = ebuf[j + 3];
        float4 v0 = g4[r0 * (NCLS / 4) + c4];
        float4 v1 = g4[r1 * (NCLS / 4) + c4];
        float4 v2 = g4[r2 * (NCLS / 4) + c4];
        float4 v3 = g4[r3 * (NCLS / 4) + c4];
        ax += v0.x; ay += v0.y; az += v0.z; aw += v0.w;
        bx += v1.x; by += v1.y; bz += v1.z; bw += v1.w;
        cx += v2.x; cy += v2.y; cz += v2.z; cw += v2.w;
        dx += v3.x; dy += v3.y; dz += v3.z; dw += v3.w;
    }
    for (; j < e; ++j) {
        float4 v = g4[ebuf[j] * (NCLS / 4) + c4];
        ax += v.x; ay += v.y; az += v.z; aw += v.w;
    }
    float4 o;
    o.x = (ax + bx + cx + dx) * dinv;
    o.y = (ay + by + cy + dy) * dinv;
    o.z = (az + bz + cz + dz) * dinv;
    o.w = (aw + bw + cw + dw) * dinv;
    reinterpret_cast<float4*>(out)[t] = o;
}

extern "C" void kernel_launch(void* const* d_in, const int* in_sizes, int n_in,
                              void* d_out, int out_size, void* d_ws, size_t ws_size,
                              hipStream_t stream) {
    const float* xE = (const float*)d_in[0];
    const float* xH = (const float*)d_in[1];
    const float* xS = (const float*)d_in[2];
    const float* W  = (const float*)d_in[3];
    const int*   ei = (const int*)d_in[4];
    const int* row = ei;            // edge_index[0]
    const int* col = ei + NE;       // edge_index[1]
    float* out = (float*)d_out;

    auto pad = [](size_t x) { return (x + 255) & ~(size_t)255; };
    char* p = (char*)d_ws;
    int* gcur  = (int*)p;               p += pad((size_t)NBKT * 4);
    int* bbase = (int*)p;               p += pad((size_t)NBKT * 4);
    int* offs  = (int*)p;               p += pad((size_t)(NN + 1) * 4);
    int* ebuf  = (int*)p;               p += pad((size_t)NE * 4);
    float* g   = (float*)p;             // NN*NCLS floats (16 MB)
    unsigned* pairs = (unsigned*)g;     // aliases g: pairs dead before h writes g

    hipMemsetAsync(gcur, 0, (size_t)NBKT * 4, stream);

    binA_kernel<<<ABLK, 256, 0, stream>>>(row, col, gcur, pairs);
    bscan_kernel<<<1, 256, 0, stream>>>(gcur, bbase);
    binB_kernel<<<NBKT, 1024, 0, stream>>>(gcur, bbase, pairs, ebuf, offs);
    h_kernel<<<(NN + HNB - 1) / HNB, HT, 0, stream>>>(xE, xH, xS, W, offs, g);
    gather_kernel<<<(NN * (NCLS / 4) + 255) / 256, 256, 0, stream>>>(offs, ebuf, g, out);
}

// Round 12
// 333.936 us; speedup vs baseline: 9.7639x; 1.0438x over previous
//
#include <hip/hip_runtime.h>
#include <math.h>

constexpr int NN   = 100000;   // nodes
constexpr int DIM  = 128;
constexpr int NE   = 3200000;  // edges
constexpr int NCLS = 40;
constexpr float EPSF = 1e-7f;

constexpr int BSH  = 9;                      // 512 cols per coarse bucket
constexpr int BSZ  = 1 << BSH;
constexpr int NBKT = (NN + BSZ - 1) >> BSH;  // 196
constexpr int CAP  = 18432;                  // bucket capacity
constexpr int AEPB = 4096;                   // edges per binA block
constexpr int ABLK = (NE + AEPB - 1) / AEPB; // 782

constexpr int QCLS = 10;                     // classes per wave (quarter)
constexpr int GNB  = 64;                     // nodes per h block
constexpr int KC   = 32;                     // k-chunk (floats)

// ---- pass A: coarse-bucket partition with LDS shuffle, coalesced run writes
__global__ __launch_bounds__(256) void binA_kernel(const int* __restrict__ row,
                                                   const int* __restrict__ col,
                                                   int* __restrict__ gcur,
                                                   unsigned* __restrict__ pairs) {
    __shared__ int hist[256];
    __shared__ int lofx[256];
    __shared__ int gbase[256];
    __shared__ unsigned sortedw[AEPB];
    __shared__ int dstg[AEPB];

    int t = threadIdx.x;
    int e0 = blockIdx.x * AEPB;
    int cnt = min(AEPB, NE - e0);

    hist[t] = 0;
    __syncthreads();
    for (int k = t; k < cnt; k += 256) atomicAdd(&hist[col[e0 + k] >> BSH], 1);
    __syncthreads();

    int h = hist[t];
    if (t < NBKT && h > 0) gbase[t] = atomicAdd(&gcur[t], h);
    lofx[t] = h;
    __syncthreads();
    for (int d = 1; d < 256; d <<= 1) {
        int o = (t >= d) ? lofx[t - d] : 0;
        __syncthreads();
        lofx[t] += o;
        __syncthreads();
    }
    int excl = lofx[t] - h;
    lofx[t] = excl;
    hist[t] = excl;
    __syncthreads();

    for (int k = t; k < cnt; k += 256) {
        int c = col[e0 + k], r = row[e0 + k];
        int b = c >> BSH;
        int pos = atomicAdd(&hist[b], 1);
        sortedw[pos] = ((unsigned)(c & (BSZ - 1)) << 17) | (unsigned)r;
        dstg[pos] = b * CAP + gbase[b] + (pos - lofx[b]);
    }
    __syncthreads();
    for (int k = t; k < cnt; k += 256) pairs[dstg[k]] = sortedw[k];
}

// ---- bucket-base exclusive scan (196 values, one block) --------------------
__global__ __launch_bounds__(256) void bscan_kernel(const int* __restrict__ gcur,
                                                    int* __restrict__ bbase) {
    __shared__ int sc[256];
    int t = threadIdx.x;
    int v = (t < NBKT) ? gcur[t] : 0;
    sc[t] = v;
    __syncthreads();
    for (int d = 1; d < 256; d <<= 1) {
        int o = (t >= d) ? sc[t - d] : 0;
        __syncthreads();
        sc[t] += o;
        __syncthreads();
    }
    if (t < NBKT) bbase[t] = sc[t] - v;
}

// ---- pass B: per-bucket counting sort in LDS; writes offs + coalesced ebuf -
__global__ __launch_bounds__(1024) void binB_kernel(const int* __restrict__ gcur,
                                                    const int* __restrict__ bbase,
                                                    const unsigned* __restrict__ pairs,
                                                    int* __restrict__ ebuf,
                                                    int* __restrict__ offs) {
    __shared__ unsigned in[CAP];
    __shared__ int srow[CAP];
    __shared__ int hist[512];
    __shared__ int sc[1024];

    int t = threadIdx.x;
    int b = blockIdx.x;
    int cnt = gcur[b];
    int base = bbase[b];
    const unsigned* pb = pairs + (size_t)b * CAP;

    for (int i = t; i < cnt; i += 1024) in[i] = pb[i];
    if (t < 512) hist[t] = 0;
    __syncthreads();
    for (int i = t; i < cnt; i += 1024) atomicAdd(&hist[in[i] >> 17], 1);
    __syncthreads();

    int v = (t < 512) ? hist[t] : 0;
    sc[t] = v;
    __syncthreads();
    for (int d = 1; d < 1024; d <<= 1) {
        int o = (t >= d) ? sc[t - d] : 0;
        __syncthreads();
        sc[t] += o;
        __syncthreads();
    }
    int excl = sc[t] - v;
    if (t < 512) {
        int c = (b << BSH) + t;
        if (c <= NN) offs[c] = base + excl;
        hist[t] = excl;
    }
    __syncthreads();
    for (int i = t; i < cnt; i += 1024) {
        unsigned w = in[i];
        int pos = atomicAdd(&hist[w >> 17], 1);
        srow[pos] = (int)(w & 0x1FFFFu);
    }
    __syncthreads();
    for (int i = t; i < cnt; i += 1024) ebuf[base + i] = srow[i];
}

__device__ __forceinline__ float f4c(const float4& v, int j) {
    return (j == 0) ? v.x : (j == 1) ? v.y : (j == 2) ? v.z : v.w;
}

// ---------------- h = concat(xE, logH, logS) @ W ; g = h * dinv -------------
// 256 thr / 64 nodes / 4 class-quarter waves. Per phase: coalesced stage of a
// 64x32 x-tile into XOR-swizzled float4 LDS; burst ds_read_b128 the lane's
// row into 8 VGPR float4s (single lgkm drain); FMA loop uses VGPR x + scalar
// s_load W only -> SMEM waits never re-drain the DS queue (the R11 killer).
__global__ __launch_bounds__(256) void h_kernel(
    const float* __restrict__ xE, const float* __restrict__ xH,
    const float* __restrict__ xS, const float* __restrict__ W,
    const int* __restrict__ offs, float* __restrict__ g) {

    __shared__ float4 tile[GNB * 8];   // 8 KB, slot' = slot ^ (row&7)
    __shared__ float x0s[GNB];
    __shared__ float scs[GNB];

    int t = threadIdx.x;
    int lane = t & 63;
    int w = __builtin_amdgcn_readfirstlane(t >> 6);   // wave-uniform quarter
    int n0 = blockIdx.x * GNB;

    float acc[QCLS];
#pragma unroll
    for (int c = 0; c < QCLS; ++c) acc[c] = 0.f;

    for (int m = 0; m < 3; ++m) {
        const float* xbase = (m == 0) ? xE : (m == 1) ? xH : xS;
#pragma unroll
        for (int kc = 0; kc < DIM / KC; ++kc) {
            __syncthreads();   // protect previous phase's tile reads
#pragma unroll
            for (int p = 0; p < 2; ++p) {
                int f4i = p * 256 + t;          // 0..511
                int row  = f4i >> 3;
                int slot = f4i & 7;
                int gr = n0 + row;
                float4 v = make_float4(0.f, 0.f, 0.f, 0.f);
                if (gr < NN)
                    v = *reinterpret_cast<const float4*>(
                        xbase + (size_t)gr * DIM + kc * KC + slot * 4);
                if (m > 0 && kc == 0 && slot == 0) {
                    x0s[row] = v.x;
                    v.x = 0.f;
                }
                tile[row * 8 + (slot ^ (row & 7))] = v;
            }
            __syncthreads();
            if (m > 0 && kc == 0) {
                if (t < GNB) {
                    float x0 = x0s[t];
                    float sc;
                    if (m == 1) {
                        sc = acoshf(fmaxf(x0, 1.f)) *
                             rsqrtf(fmaxf(x0 * x0 - 1.f, EPSF));
                    } else {
                        float cc = fminf(fmaxf(x0, -1.f), 1.f);
                        sc = acosf(cc) * rsqrtf(fmaxf(1.f - x0 * x0, EPSF));
                    }
                    scs[t] = sc;
                }
                __syncthreads();
            }
            float scm = (m == 0) ? 1.f : scs[lane];

            // burst: lane's whole 32-float row -> 8 VGPR float4s
            float4 tx[8];
#pragma unroll
            for (int s = 0; s < 8; ++s)
                tx[s] = tile[lane * 8 + (s ^ (lane & 7))];

            const float* wb = W + (size_t)(m * DIM + kc * KC) * NCLS + w * QCLS;
#pragma unroll
            for (int k = 0; k < KC; ++k) {
                float xk = f4c(tx[k >> 2], k & 3) * scm;
#pragma unroll
                for (int c = 0; c < QCLS; ++c)
                    acc[c] = fmaf(xk, wb[k * NCLS + c], acc[c]);
            }
        }
    }

    int n = n0 + lane;
    if (n >= NN) return;

    float dinv = rsqrtf((float)(offs[n + 1] - offs[n] + 1));  // +1 self loop
    float* gn = g + (size_t)n * NCLS + w * QCLS;
#pragma unroll
    for (int c2 = 0; c2 < QCLS / 2; ++c2) {
        float a = acc[c2 * 2] * dinv;
        float b = acc[c2 * 2 + 1] * dinv;
        *reinterpret_cast<float2*>(gn + c2 * 2) = make_float2(a, b);
    }
}

// ------ gather: float4 per thread (10 threads/node), 4x unrolled edge loop ---
__global__ __launch_bounds__(256) void gather_kernel(
    const int* __restrict__ offs, const int* __restrict__ ebuf,
    const float* __restrict__ g, float* __restrict__ out) {
    int t = blockIdx.x * blockDim.x + threadIdx.x;
    if (t >= NN * (NCLS / 4)) return;
    int n  = t / (NCLS / 4);
    int c4 = t - n * (NCLS / 4);

    int s = offs[n], e = offs[n + 1];
    float dinv = rsqrtf((float)(e - s + 1));
    const float4* g4 = reinterpret_cast<const float4*>(g);
    float4 a = g4[n * (NCLS / 4) + c4];      // self loop (dinv[n] folded in g)
    float ax = a.x, ay = a.y, az = a.z, aw = a.w;
    float bx = 0.f, by = 0.f, bz = 0.f, bw = 0.f;
    float cx = 0.f, cy = 0.f, cz = 0.f, cw = 0.f;
    float dx = 0.f, dy = 0.f, dz = 0.f, dw = 0.f;
    int j = s;
    for (; j + 3 < e; j += 4) {
        int r0 = ebuf[j], r1 = ebuf[j + 1], r2 = ebuf[j + 2], r3 = ebuf[j + 3];
        float4 v0 = g4[r0 * (NCLS / 4) + c4];
        float4 v1 = g4[r1 * (NCLS / 4) + c4];
        float4 v2 = g4[r2 * (NCLS / 4) + c4];
        float4 v3 = g4[r3 * (NCLS / 4) + c4];
        ax += v0.x; ay += v0.y; az += v0.z; aw += v0.w;
        bx += v1.x; by += v1.y; bz += v1.z; bw += v1.w;
        cx += v2.x; cy += v2.y; cz += v2.z; cw += v2.w;
        dx += v3.x; dy += v3.y; dz += v3.z; dw += v3.w;
    }
    for (; j < e; ++j) {
        float4 v = g4[ebuf[j] * (NCLS / 4) + c4];
        ax += v.x; ay += v.y; az += v.z; aw += v.w;
    }
    float4 o;
    o.x = (ax + bx + cx + dx) * dinv;
    o.y = (ay + by + cy + dy) * dinv;
    o.z = (az + bz + cz + dz) * dinv;
    o.w = (aw + bw + cw + dw) * dinv;
    reinterpret_cast<float4*>(out)[t] = o;
}

extern "C" void kernel_launch(void* const* d_in, const int* in_sizes, int n_in,
                              void* d_out, int out_size, void* d_ws, size_t ws_size,
                              hipStream_t stream) {
    const float* xE = (const float*)d_in[0];
    const float* xH = (const float*)d_in[1];
    const float* xS = (const float*)d_in[2];
    const float* W  = (const float*)d_in[3];
    const int*   ei = (const int*)d_in[4];
    const int* row = ei;            // edge_index[0]
    const int* col = ei + NE;       // edge_index[1]
    float* out = (float*)d_out;

    auto pad = [](size_t x) { return (x + 255) & ~(size_t)255; };
    char* p = (char*)d_ws;
    int* gcur  = (int*)p;               p += pad((size_t)NBKT * 4);
    int* bbase = (int*)p;               p += pad((size_t)NBKT * 4);
    int* offs  = (int*)p;               p += pad((size_t)(NN + 1) * 4);
    int* ebuf  = (int*)p;               p += pad((size_t)NE * 4);
    float* g   = (float*)p;             // NN*NCLS floats (16 MB)
    unsigned* pairs = (unsigned*)g;     // aliases g: pairs dead before h writes g

    hipMemsetAsync(gcur, 0, (size_t)NBKT * 4, stream);

    binA_kernel<<<ABLK, 256, 0, stream>>>(row, col, gcur, pairs);
    bscan_kernel<<<1, 256, 0, stream>>>(gcur, bbase);
    binB_kernel<<<NBKT, 1024, 0, stream>>>(gcur, bbase, pairs, ebuf, offs);
    h_kernel<<<(NN + GNB - 1) / GNB, 256, 0, stream>>>(xE, xH, xS, W, offs, g);
    gather_kernel<<<(NN * (NCLS / 4) + 255) / 256, 256, 0, stream>>>(offs, ebuf, g, out);
}

// Round 13
// 195.393 us; speedup vs baseline: 16.6870x; 1.7090x over previous
//
#include <hip/hip_runtime.h>
#include <math.h>

constexpr int NN   = 100000;   // nodes
constexpr int DIM  = 128;
constexpr int NE   = 3200000;  // edges
constexpr int NCLS = 40;
constexpr float EPSF = 1e-7f;

constexpr int BSH  = 9;                      // 512 cols per coarse bucket
constexpr int BSZ  = 1 << BSH;
constexpr int NBKT = (NN + BSZ - 1) >> BSH;  // 196
constexpr int CAP  = 18432;                  // bucket capacity
constexpr int AEPB = 4096;                   // edges per binA block
constexpr int ABLK = (NE + AEPB - 1) / AEPB; // 782

constexpr int TP   = 36;                     // x-tile row pitch (floats)

typedef __attribute__((ext_vector_type(8))) short bf16x8;
typedef __attribute__((ext_vector_type(4))) float f32x4;

__device__ __forceinline__ unsigned short f2bf(float f) {
    unsigned u = __builtin_bit_cast(unsigned, f);
    unsigned r = u + 0x7FFFu + ((u >> 16) & 1u);
    return (unsigned short)(r >> 16);
}
__device__ __forceinline__ float bf2f(unsigned short b) {
    return __builtin_bit_cast(float, (unsigned)b << 16);
}

// ---- pass A: coarse-bucket partition with LDS shuffle, coalesced run writes
__global__ __launch_bounds__(256) void binA_kernel(const int* __restrict__ row,
                                                   const int* __restrict__ col,
                                                   int* __restrict__ gcur,
                                                   unsigned* __restrict__ pairs) {
    __shared__ int hist[256];
    __shared__ int lofx[256];
    __shared__ int gbase[256];
    __shared__ unsigned sortedw[AEPB];
    __shared__ int dstg[AEPB];

    int t = threadIdx.x;
    int e0 = blockIdx.x * AEPB;
    int cnt = min(AEPB, NE - e0);

    hist[t] = 0;
    __syncthreads();
    for (int k = t; k < cnt; k += 256) atomicAdd(&hist[col[e0 + k] >> BSH], 1);
    __syncthreads();

    int h = hist[t];
    if (t < NBKT && h > 0) gbase[t] = atomicAdd(&gcur[t], h);
    lofx[t] = h;
    __syncthreads();
    for (int d = 1; d < 256; d <<= 1) {
        int o = (t >= d) ? lofx[t - d] : 0;
        __syncthreads();
        lofx[t] += o;
        __syncthreads();
    }
    int excl = lofx[t] - h;
    lofx[t] = excl;
    hist[t] = excl;
    __syncthreads();

    for (int k = t; k < cnt; k += 256) {
        int c = col[e0 + k], r = row[e0 + k];
        int b = c >> BSH;
        int pos = atomicAdd(&hist[b], 1);
        sortedw[pos] = ((unsigned)(c & (BSZ - 1)) << 17) | (unsigned)r;
        dstg[pos] = b * CAP + gbase[b] + (pos - lofx[b]);
    }
    __syncthreads();
    for (int k = t; k < cnt; k += 256) pairs[dstg[k]] = sortedw[k];
}

// ---- bucket-base exclusive scan (196 values, one block) --------------------
__global__ __launch_bounds__(256) void bscan_kernel(const int* __restrict__ gcur,
                                                    int* __restrict__ bbase) {
    __shared__ int sc[256];
    int t = threadIdx.x;
    int v = (t < NBKT) ? gcur[t] : 0;
    sc[t] = v;
    __syncthreads();
    for (int d = 1; d < 256; d <<= 1) {
        int o = (t >= d) ? sc[t - d] : 0;
        __syncthreads();
        sc[t] += o;
        __syncthreads();
    }
    if (t < NBKT) bbase[t] = sc[t] - v;
}

// ---- pass B: per-bucket counting sort in LDS; writes offs + coalesced ebuf -
__global__ __launch_bounds__(1024) void binB_kernel(const int* __restrict__ gcur,
                                                    const int* __restrict__ bbase,
                                                    const unsigned* __restrict__ pairs,
                                                    int* __restrict__ ebuf,
                                                    int* __restrict__ offs) {
    __shared__ unsigned in[CAP];
    __shared__ int srow[CAP];
    __shared__ int hist[512];
    __shared__ int sc[1024];

    int t = threadIdx.x;
    int b = blockIdx.x;
    int cnt = gcur[b];
    int base = bbase[b];
    const unsigned* pb = pairs + (size_t)b * CAP;

    for (int i = t; i < cnt; i += 1024) in[i] = pb[i];
    if (t < 512) hist[t] = 0;
    __syncthreads();
    for (int i = t; i < cnt; i += 1024) atomicAdd(&hist[in[i] >> 17], 1);
    __syncthreads();

    int v = (t < 512) ? hist[t] : 0;
    sc[t] = v;
    __syncthreads();
    for (int d = 1; d < 1024; d <<= 1) {
        int o = (t >= d) ? sc[t - d] : 0;
        __syncthreads();
        sc[t] += o;
        __syncthreads();
    }
    int excl = sc[t] - v;
    if (t < 512) {
        int c = (b << BSH) + t;
        if (c <= NN) offs[c] = base + excl;
        hist[t] = excl;
    }
    __syncthreads();
    for (int i = t; i < cnt; i += 1024) {
        unsigned w = in[i];
        int pos = atomicAdd(&hist[w >> 17], 1);
        srow[pos] = (int)(w & 0x1FFFFu);
    }
    __syncthreads();
    for (int i = t; i < cnt; i += 1024) ebuf[base + i] = srow[i];
}

// ---- wpack: W[384][40] f32 -> hi/lo bf16 B-fragments in MFMA lane order ----
// layout: frag = ((kc*3 + t)*2 + hl)*64 + lane ; element j = k-slice
// B[k = kc*32 + 8*(lane>>4) + j][class = 16*t + (lane&15)], class>=40 -> 0.
__global__ __launch_bounds__(256) void wpack_kernel(const float* __restrict__ W,
                                                    unsigned short* __restrict__ wbf) {
    int idx = blockIdx.x * 256 + threadIdx.x;
    if (idx >= 12 * 3 * 2 * 64 * 8) return;
    int j    = idx & 7;
    int lane = (idx >> 3) & 63;
    int hl   = (idx >> 9) & 1;
    int rest = idx >> 10;          // kc*3 + t
    int t    = rest % 3;
    int kc   = rest / 3;
    int k = kc * 32 + 8 * (lane >> 4) + j;
    int c = 16 * t + (lane & 15);
    float w = (c < NCLS) ? W[k * NCLS + c] : 0.f;
    unsigned short hi = f2bf(w);
    wbf[idx] = (hl == 0) ? hi : f2bf(w - bf2f(hi));
}

// ---------------- h = concat(xE, logH, logS) @ W ; g = h * dinv -------------
// MFMA 16x16x32 bf16 with full hi/lo split (3 terms). Block = 4 waves x 64
// nodes; wave wv owns nodes [n0+16wv, +16) x all 40 classes (3 C-tiles).
// Per (m,kc): coalesced-stage 64x32 f32 x-tile -> LDS (pitch 36, conflict-
// free), build A hi/lo frags, load 6 prepacked B frags (coalesced b128),
// 9 MFMAs. W never touches the scalar pipe (the R8-R12 limiter).
__global__ __launch_bounds__(256) void h_kernel(
    const float* __restrict__ xE, const float* __restrict__ xH,
    const float* __restrict__ xS, const unsigned short* __restrict__ wbf,
    const int* __restrict__ offs, float* __restrict__ g) {

    __shared__ float tile[64 * TP];
    __shared__ float x0s[64];
    __shared__ float scs[64];
    __shared__ float dl[64];

    int t = threadIdx.x;
    int lane = t & 63;
    int wv = t >> 6;                 // wave id 0..3
    int n0 = blockIdx.x * 64;
    int r  = lane & 15;              // A row / C col
    int kq = lane >> 4;              // k-quarter

    if (t < 64) {
        int n = n0 + t;
        int d = (n < NN) ? (offs[n + 1] - offs[n]) : 0;
        dl[t] = rsqrtf((float)(d + 1));    // +1 self loop
    }

    f32x4 acc0 = {0.f, 0.f, 0.f, 0.f};
    f32x4 acc1 = acc0, acc2 = acc0;

    const bf16x8* wfr = reinterpret_cast<const bf16x8*>(wbf);

    for (int m = 0; m < 3; ++m) {
        const float* xb = (m == 0) ? xE : (m == 1) ? xH : xS;
#pragma unroll
        for (int kc4 = 0; kc4 < 4; ++kc4) {
            __syncthreads();   // protect previous phase's tile reads
#pragma unroll
            for (int p = 0; p < 2; ++p) {
                int f4i = p * 256 + t;          // 0..511
                int row  = f4i >> 3;
                int slot = f4i & 7;
                int gr = n0 + row;
                float4 v = make_float4(0.f, 0.f, 0.f, 0.f);
                if (gr < NN)
                    v = *reinterpret_cast<const float4*>(
                        xb + (size_t)gr * DIM + kc4 * 32 + slot * 4);
                if (m > 0 && kc4 == 0 && slot == 0) {
                    x0s[row] = v.x;
                    v.x = 0.f;
                }
                float* d = &tile[row * TP + slot * 4];
                d[0] = v.x; d[1] = v.y; d[2] = v.z; d[3] = v.w;
            }
            __syncthreads();
            if (m > 0 && kc4 == 0) {
                if (t < 64) {
                    float x0 = x0s[t];
                    float sc;
                    if (m == 1) {
                        sc = acoshf(fmaxf(x0, 1.f)) *
                             rsqrtf(fmaxf(x0 * x0 - 1.f, EPSF));
                    } else {
                        float cc = fminf(fmaxf(x0, -1.f), 1.f);
                        sc = acosf(cc) * rsqrtf(fmaxf(1.f - x0 * x0, EPSF));
                    }
                    scs[t] = sc;
                }
                __syncthreads();
            }
            float scm = (m == 0) ? 1.f : scs[16 * wv + r];

            // A frags: node = n0+16wv+r, k = kc4*32 + 8*kq + j
            const float* trow = &tile[(16 * wv + r) * TP + kq * 8];
            bf16x8 ah, al;
#pragma unroll
            for (int j = 0; j < 8; ++j) {
                float a = trow[j] * scm;
                unsigned short hbits = f2bf(a);
                ah[j] = (short)hbits;
                al[j] = (short)f2bf(a - bf2f(hbits));
            }

            int kc = m * 4 + kc4;
            const bf16x8* wb = wfr + (size_t)(kc * 3) * 2 * 64;
            bf16x8 bh0 = wb[0 * 128 + 0 * 64 + lane];
            bf16x8 bl0 = wb[0 * 128 + 1 * 64 + lane];
            bf16x8 bh1 = wb[1 * 128 + 0 * 64 + lane];
            bf16x8 bl1 = wb[1 * 128 + 1 * 64 + lane];
            bf16x8 bh2 = wb[2 * 128 + 0 * 64 + lane];
            bf16x8 bl2 = wb[2 * 128 + 1 * 64 + lane];

            acc0 = __builtin_amdgcn_mfma_f32_16x16x32_bf16(ah, bh0, acc0, 0, 0, 0);
            acc0 = __builtin_amdgcn_mfma_f32_16x16x32_bf16(al, bh0, acc0, 0, 0, 0);
            acc0 = __builtin_amdgcn_mfma_f32_16x16x32_bf16(ah, bl0, acc0, 0, 0, 0);
            acc1 = __builtin_amdgcn_mfma_f32_16x16x32_bf16(ah, bh1, acc1, 0, 0, 0);
            acc1 = __builtin_amdgcn_mfma_f32_16x16x32_bf16(al, bh1, acc1, 0, 0, 0);
            acc1 = __builtin_amdgcn_mfma_f32_16x16x32_bf16(ah, bl1, acc1, 0, 0, 0);
            acc2 = __builtin_amdgcn_mfma_f32_16x16x32_bf16(ah, bh2, acc2, 0, 0, 0);
            acc2 = __builtin_amdgcn_mfma_f32_16x16x32_bf16(al, bh2, acc2, 0, 0, 0);
            acc2 = __builtin_amdgcn_mfma_f32_16x16x32_bf16(ah, bl2, acc2, 0, 0, 0);
        }
    }

    // C/D: node = n0 + 16wv + 4*kq + i ; class = 16t + r   [m89 layout]
#pragma unroll
    for (int i = 0; i < 4; ++i) {
        int nl = 16 * wv + 4 * kq + i;
        int n = n0 + nl;
        if (n < NN) {
            float di = dl[nl];
            g[(size_t)n * NCLS + r]      = acc0[i] * di;
            g[(size_t)n * NCLS + 16 + r] = acc1[i] * di;
            if (r < 8)
                g[(size_t)n * NCLS + 32 + r] = acc2[i] * di;
        }
    }
}

// ------ gather: float4 per thread (10 threads/node), 4x unrolled edge loop ---
__global__ __launch_bounds__(256) void gather_kernel(
    const int* __restrict__ offs, const int* __restrict__ ebuf,
    const float* __restrict__ g, float* __restrict__ out) {
    int t = blockIdx.x * blockDim.x + threadIdx.x;
    if (t >= NN * (NCLS / 4)) return;
    int n  = t / (NCLS / 4);
    int c4 = t - n * (NCLS / 4);

    int s = offs[n], e = offs[n + 1];
    float dinv = rsqrtf((float)(e - s + 1));
    const float4* g4 = reinterpret_cast<const float4*>(g);
    float4 a = g4[n * (NCLS / 4) + c4];      // self loop (dinv[n] folded in g)
    float ax = a.x, ay = a.y, az = a.z, aw = a.w;
    float bx = 0.f, by = 0.f, bz = 0.f, bw = 0.f;
    float cx = 0.f, cy = 0.f, cz = 0.f, cw = 0.f;
    float dx = 0.f, dy = 0.f, dz = 0.f, dw = 0.f;
    int j = s;
    for (; j + 3 < e; j += 4) {
        int r0 = ebuf[j], r1 = ebuf[j + 1], r2 = ebuf[j + 2], r3 = ebuf[j + 3];
        float4 v0 = g4[r0 * (NCLS / 4) + c4];
        float4 v1 = g4[r1 * (NCLS / 4) + c4];
        float4 v2 = g4[r2 * (NCLS / 4) + c4];
        float4 v3 = g4[r3 * (NCLS / 4) + c4];
        ax += v0.x; ay += v0.y; az += v0.z; aw += v0.w;
        bx += v1.x; by += v1.y; bz += v1.z; bw += v1.w;
        cx += v2.x; cy += v2.y; cz += v2.z; cw += v2.w;
        dx += v3.x; dy += v3.y; dz += v3.z; dw += v3.w;
    }
    for (; j < e; ++j) {
        float4 v = g4[ebuf[j] * (NCLS / 4) + c4];
        ax += v.x; ay += v.y; az += v.z; aw += v.w;
    }
    float4 o;
    o.x = (ax + bx + cx + dx) * dinv;
    o.y = (ay + by + cy + dy) * dinv;
    o.z = (az + bz + cz + dz) * dinv;
    o.w = (aw + bw + cw + dw) * dinv;
    reinterpret_cast<float4*>(out)[t] = o;
}

extern "C" void kernel_launch(void* const* d_in, const int* in_sizes, int n_in,
                              void* d_out, int out_size, void* d_ws, size_t ws_size,
                              hipStream_t stream) {
    const float* xE = (const float*)d_in[0];
    const float* xH = (const float*)d_in[1];
    const float* xS = (const float*)d_in[2];
    const float* W  = (const float*)d_in[3];
    const int*   ei = (const int*)d_in[4];
    const int* row = ei;            // edge_index[0]
    const int* col = ei + NE;       // edge_index[1]
    float* out = (float*)d_out;

    auto pad = [](size_t x) { return (x + 255) & ~(size_t)255; };
    char* p = (char*)d_ws;
    int* gcur  = (int*)p;               p += pad((size_t)NBKT * 4);
    int* bbase = (int*)p;               p += pad((size_t)NBKT * 4);
    int* offs  = (int*)p;               p += pad((size_t)(NN + 1) * 4);
    int* ebuf  = (int*)p;               p += pad((size_t)NE * 4);
    float* g   = (float*)p;             p += pad((size_t)NN * NCLS * 4);  // 16 MB
    unsigned short* wbf = (unsigned short*)p;   // 147456 B
    unsigned* pairs = (unsigned*)g;     // aliases g: pairs dead before h writes g

    hipMemsetAsync(gcur, 0, (size_t)NBKT * 4, stream);

    wpack_kernel<<<(12 * 3 * 2 * 64 * 8 + 255) / 256, 256, 0, stream>>>(W, wbf);
    binA_kernel<<<ABLK, 256, 0, stream>>>(row, col, gcur, pairs);
    bscan_kernel<<<1, 256, 0, stream>>>(gcur, bbase);
    binB_kernel<<<NBKT, 1024, 0, stream>>>(gcur, bbase, pairs, ebuf, offs);
    h_kernel<<<(NN + 63) / 64, 256, 0, stream>>>(xE, xH, xS, wbf, offs, g);
    gather_kernel<<<(NN * (NCLS / 4) + 255) / 256, 256, 0, stream>>>(offs, ebuf, g, out);
}

// Round 14
// 167.933 us; speedup vs baseline: 19.4157x; 1.1635x over previous
//
#include <hip/hip_runtime.h>
#include <math.h>

constexpr int NN   = 100000;   // nodes
constexpr int DIM  = 128;
constexpr int NE   = 3200000;  // edges
constexpr int NCLS = 40;
constexpr float EPSF = 1e-7f;

constexpr int BSH  = 9;                      // 512 cols per coarse bucket
constexpr int BSZ  = 1 << BSH;
constexpr int NBKT = (NN + BSZ - 1) >> BSH;  // 196
constexpr int CAP  = 18432;                  // bucket capacity
constexpr int AEPB = 4096;                   // edges per binA block
constexpr int ABLK = (NE + AEPB - 1) / AEPB; // 782

constexpr int TP   = 36;                     // x-tile row pitch (floats)

typedef __attribute__((ext_vector_type(8))) short bf16x8;
typedef __attribute__((ext_vector_type(8))) unsigned short u16x8;
typedef __attribute__((ext_vector_type(4))) float f32x4;

__device__ __forceinline__ unsigned short f2bf(float f) {
    unsigned u = __builtin_bit_cast(unsigned, f);
    unsigned r = u + 0x7FFFu + ((u >> 16) & 1u);
    return (unsigned short)(r >> 16);
}
__device__ __forceinline__ float bf2f(unsigned short b) {
    return __builtin_bit_cast(float, (unsigned)b << 16);
}

// ---- pass A: coarse-bucket partition with LDS shuffle, coalesced run writes
__global__ __launch_bounds__(256) void binA_kernel(const int* __restrict__ row,
                                                   const int* __restrict__ col,
                                                   int* __restrict__ gcur,
                                                   unsigned* __restrict__ pairs) {
    __shared__ int hist[256];
    __shared__ int lofx[256];
    __shared__ int gbase[256];
    __shared__ unsigned sortedw[AEPB];
    __shared__ int dstg[AEPB];

    int t = threadIdx.x;
    int e0 = blockIdx.x * AEPB;
    int cnt = min(AEPB, NE - e0);

    hist[t] = 0;
    __syncthreads();
    for (int k = t; k < cnt; k += 256) atomicAdd(&hist[col[e0 + k] >> BSH], 1);
    __syncthreads();

    int h = hist[t];
    if (t < NBKT && h > 0) gbase[t] = atomicAdd(&gcur[t], h);
    lofx[t] = h;
    __syncthreads();
    for (int d = 1; d < 256; d <<= 1) {
        int o = (t >= d) ? lofx[t - d] : 0;
        __syncthreads();
        lofx[t] += o;
        __syncthreads();
    }
    int excl = lofx[t] - h;
    lofx[t] = excl;
    hist[t] = excl;
    __syncthreads();

    for (int k = t; k < cnt; k += 256) {
        int c = col[e0 + k], r = row[e0 + k];
        int b = c >> BSH;
        int pos = atomicAdd(&hist[b], 1);
        sortedw[pos] = ((unsigned)(c & (BSZ - 1)) << 17) | (unsigned)r;
        dstg[pos] = b * CAP + gbase[b] + (pos - lofx[b]);
    }
    __syncthreads();
    for (int k = t; k < cnt; k += 256) pairs[dstg[k]] = sortedw[k];
}

// ---- bucket-base exclusive scan (196 values, one block) --------------------
__global__ __launch_bounds__(256) void bscan_kernel(const int* __restrict__ gcur,
                                                    int* __restrict__ bbase) {
    __shared__ int sc[256];
    int t = threadIdx.x;
    int v = (t < NBKT) ? gcur[t] : 0;
    sc[t] = v;
    __syncthreads();
    for (int d = 1; d < 256; d <<= 1) {
        int o = (t >= d) ? sc[t - d] : 0;
        __syncthreads();
        sc[t] += o;
        __syncthreads();
    }
    if (t < NBKT) bbase[t] = sc[t] - v;
}

// ---- pass B: per-bucket counting sort in LDS; writes offs + coalesced ebuf -
__global__ __launch_bounds__(1024) void binB_kernel(const int* __restrict__ gcur,
                                                    const int* __restrict__ bbase,
                                                    const unsigned* __restrict__ pairs,
                                                    int* __restrict__ ebuf,
                                                    int* __restrict__ offs) {
    __shared__ unsigned in[CAP];
    __shared__ int srow[CAP];
    __shared__ int hist[512];
    __shared__ int sc[1024];

    int t = threadIdx.x;
    int b = blockIdx.x;
    int cnt = gcur[b];
    int base = bbase[b];
    const unsigned* pb = pairs + (size_t)b * CAP;

    for (int i = t; i < cnt; i += 1024) in[i] = pb[i];
    if (t < 512) hist[t] = 0;
    __syncthreads();
    for (int i = t; i < cnt; i += 1024) atomicAdd(&hist[in[i] >> 17], 1);
    __syncthreads();

    int v = (t < 512) ? hist[t] : 0;
    sc[t] = v;
    __syncthreads();
    for (int d = 1; d < 1024; d <<= 1) {
        int o = (t >= d) ? sc[t - d] : 0;
        __syncthreads();
        sc[t] += o;
        __syncthreads();
    }
    int excl = sc[t] - v;
    if (t < 512) {
        int c = (b << BSH) + t;
        if (c <= NN) offs[c] = base + excl;
        hist[t] = excl;
    }
    __syncthreads();
    for (int i = t; i < cnt; i += 1024) {
        unsigned w = in[i];
        int pos = atomicAdd(&hist[w >> 17], 1);
        srow[pos] = (int)(w & 0x1FFFFu);
    }
    __syncthreads();
    for (int i = t; i < cnt; i += 1024) ebuf[base + i] = srow[i];
}

// ---- wpack: W[384][40] f32 -> hi/lo bf16 B-fragments in MFMA lane order ----
__global__ __launch_bounds__(256) void wpack_kernel(const float* __restrict__ W,
                                                    unsigned short* __restrict__ wbf) {
    int idx = blockIdx.x * 256 + threadIdx.x;
    if (idx >= 12 * 3 * 2 * 64 * 8) return;
    int j    = idx & 7;
    int lane = (idx >> 3) & 63;
    int hl   = (idx >> 9) & 1;
    int rest = idx >> 10;          // kc*3 + t
    int t    = rest % 3;
    int kc   = rest / 3;
    int k = kc * 32 + 8 * (lane >> 4) + j;
    int c = 16 * t + (lane & 15);
    float w = (c < NCLS) ? W[k * NCLS + c] : 0.f;
    unsigned short hi = f2bf(w);
    wbf[idx] = (hl == 0) ? hi : f2bf(w - bf2f(hi));
}

// ---------------- h = concat(xE, logH, logS) @ W ; g = h * dinv (bf16 out) --
__global__ __launch_bounds__(256) void h_kernel(
    const float* __restrict__ xE, const float* __restrict__ xH,
    const float* __restrict__ xS, const unsigned short* __restrict__ wbf,
    const int* __restrict__ offs, unsigned short* __restrict__ gbf) {

    __shared__ float tile[64 * TP];
    __shared__ float x0s[64];
    __shared__ float scs[64];
    __shared__ float dl[64];

    int t = threadIdx.x;
    int lane = t & 63;
    int wv = t >> 6;                 // wave id 0..3
    int n0 = blockIdx.x * 64;
    int r  = lane & 15;              // A row / C col
    int kq = lane >> 4;              // k-quarter

    if (t < 64) {
        int n = n0 + t;
        int d = (n < NN) ? (offs[n + 1] - offs[n]) : 0;
        dl[t] = rsqrtf((float)(d + 1));    // +1 self loop
    }

    f32x4 acc0 = {0.f, 0.f, 0.f, 0.f};
    f32x4 acc1 = acc0, acc2 = acc0;

    const bf16x8* wfr = reinterpret_cast<const bf16x8*>(wbf);

    for (int m = 0; m < 3; ++m) {
        const float* xb = (m == 0) ? xE : (m == 1) ? xH : xS;
#pragma unroll
        for (int kc4 = 0; kc4 < 4; ++kc4) {
            __syncthreads();   // protect previous phase's tile reads
#pragma unroll
            for (int p = 0; p < 2; ++p) {
                int f4i = p * 256 + t;          // 0..511
                int row  = f4i >> 3;
                int slot = f4i & 7;
                int gr = n0 + row;
                float4 v = make_float4(0.f, 0.f, 0.f, 0.f);
                if (gr < NN)
                    v = *reinterpret_cast<const float4*>(
                        xb + (size_t)gr * DIM + kc4 * 32 + slot * 4);
                if (m > 0 && kc4 == 0 && slot == 0) {
                    x0s[row] = v.x;
                    v.x = 0.f;
                }
                float* d = &tile[row * TP + slot * 4];
                d[0] = v.x; d[1] = v.y; d[2] = v.z; d[3] = v.w;
            }
            __syncthreads();
            if (m > 0 && kc4 == 0) {
                if (t < 64) {
                    float x0 = x0s[t];
                    float sc;
                    if (m == 1) {
                        sc = acoshf(fmaxf(x0, 1.f)) *
                             rsqrtf(fmaxf(x0 * x0 - 1.f, EPSF));
                    } else {
                        float cc = fminf(fmaxf(x0, -1.f), 1.f);
                        sc = acosf(cc) * rsqrtf(fmaxf(1.f - x0 * x0, EPSF));
                    }
                    scs[t] = sc;
                }
                __syncthreads();
            }
            float scm = (m == 0) ? 1.f : scs[16 * wv + r];

            // A frags: node = n0+16wv+r, k = kc4*32 + 8*kq + j
            const float* trow = &tile[(16 * wv + r) * TP + kq * 8];
            bf16x8 ah, al;
#pragma unroll
            for (int j = 0; j < 8; ++j) {
                float a = trow[j] * scm;
                unsigned short hbits = f2bf(a);
                ah[j] = (short)hbits;
                al[j] = (short)f2bf(a - bf2f(hbits));
            }

            int kc = m * 4 + kc4;
            const bf16x8* wb = wfr + (size_t)(kc * 3) * 2 * 64;
            bf16x8 bh0 = wb[0 * 128 + 0 * 64 + lane];
            bf16x8 bl0 = wb[0 * 128 + 1 * 64 + lane];
            bf16x8 bh1 = wb[1 * 128 + 0 * 64 + lane];
            bf16x8 bl1 = wb[1 * 128 + 1 * 64 + lane];
            bf16x8 bh2 = wb[2 * 128 + 0 * 64 + lane];
            bf16x8 bl2 = wb[2 * 128 + 1 * 64 + lane];

            acc0 = __builtin_amdgcn_mfma_f32_16x16x32_bf16(ah, bh0, acc0, 0, 0, 0);
            acc0 = __builtin_amdgcn_mfma_f32_16x16x32_bf16(al, bh0, acc0, 0, 0, 0);
            acc0 = __builtin_amdgcn_mfma_f32_16x16x32_bf16(ah, bl0, acc0, 0, 0, 0);
            acc1 = __builtin_amdgcn_mfma_f32_16x16x32_bf16(ah, bh1, acc1, 0, 0, 0);
            acc1 = __builtin_amdgcn_mfma_f32_16x16x32_bf16(al, bh1, acc1, 0, 0, 0);
            acc1 = __builtin_amdgcn_mfma_f32_16x16x32_bf16(ah, bl1, acc1, 0, 0, 0);
            acc2 = __builtin_amdgcn_mfma_f32_16x16x32_bf16(ah, bh2, acc2, 0, 0, 0);
            acc2 = __builtin_amdgcn_mfma_f32_16x16x32_bf16(al, bh2, acc2, 0, 0, 0);
            acc2 = __builtin_amdgcn_mfma_f32_16x16x32_bf16(ah, bl2, acc2, 0, 0, 0);
        }
    }

    // C/D: node = n0 + 16wv + 4*kq + i ; class = 16t + r   [m89 layout]
#pragma unroll
    for (int i = 0; i < 4; ++i) {
        int nl = 16 * wv + 4 * kq + i;
        int n = n0 + nl;
        if (n < NN) {
            float di = dl[nl];
            unsigned short* gr = gbf + (size_t)n * NCLS;
            gr[r]      = f2bf(acc0[i] * di);
            gr[16 + r] = f2bf(acc1[i] * di);
            if (r < 8)
                gr[32 + r] = f2bf(acc2[i] * di);
        }
    }
}

// ------ gather: bf16 g, 5 threads/node x bf16x8, 2x unrolled edge loop ------
__global__ __launch_bounds__(256) void gather_kernel(
    const int* __restrict__ offs, const int* __restrict__ ebuf,
    const unsigned short* __restrict__ gbf, float* __restrict__ out) {
    int t = blockIdx.x * blockDim.x + threadIdx.x;
    if (t >= NN * 5) return;
    int n  = t / 5;
    int c8 = t - n * 5;

    const u16x8* gb = reinterpret_cast<const u16x8*>(gbf) + c8;
    int s = offs[n], e = offs[n + 1];
    float dinv = rsqrtf((float)(e - s + 1));

    u16x8 sv = gb[n * 5];            // self loop (dinv[n] folded in g)
    float a0[8], a1[8];
#pragma unroll
    for (int k = 0; k < 8; ++k) { a0[k] = bf2f(sv[k]); a1[k] = 0.f; }

    int j = s;
    for (; j + 1 < e; j += 2) {
        int r0 = ebuf[j], r1 = ebuf[j + 1];
        u16x8 v0 = gb[r0 * 5];
        u16x8 v1 = gb[r1 * 5];
#pragma unroll
        for (int k = 0; k < 8; ++k) { a0[k] += bf2f(v0[k]); a1[k] += bf2f(v1[k]); }
    }
    if (j < e) {
        u16x8 v = gb[ebuf[j] * 5];
#pragma unroll
        for (int k = 0; k < 8; ++k) a0[k] += bf2f(v[k]);
    }

    float* on = out + (size_t)n * NCLS + c8 * 8;
    float4 o0, o1;
    o0.x = (a0[0] + a1[0]) * dinv;
    o0.y = (a0[1] + a1[1]) * dinv;
    o0.z = (a0[2] + a1[2]) * dinv;
    o0.w = (a0[3] + a1[3]) * dinv;
    o1.x = (a0[4] + a1[4]) * dinv;
    o1.y = (a0[5] + a1[5]) * dinv;
    o1.z = (a0[6] + a1[6]) * dinv;
    o1.w = (a0[7] + a1[7]) * dinv;
    *reinterpret_cast<float4*>(on)     = o0;
    *reinterpret_cast<float4*>(on + 4) = o1;
}

extern "C" void kernel_launch(void* const* d_in, const int* in_sizes, int n_in,
                              void* d_out, int out_size, void* d_ws, size_t ws_size,
                              hipStream_t stream) {
    const float* xE = (const float*)d_in[0];
    const float* xH = (const float*)d_in[1];
    const float* xS = (const float*)d_in[2];
    const float* W  = (const float*)d_in[3];
    const int*   ei = (const int*)d_in[4];
    const int* row = ei;            // edge_index[0]
    const int* col = ei + NE;       // edge_index[1]
    float* out = (float*)d_out;

    auto pad = [](size_t x) { return (x + 255) & ~(size_t)255; };
    char* p = (char*)d_ws;
    int* gcur  = (int*)p;               p += pad((size_t)NBKT * 4);
    int* bbase = (int*)p;               p += pad((size_t)NBKT * 4);
    int* offs  = (int*)p;               p += pad((size_t)(NN + 1) * 4);
    int* ebuf  = (int*)p;               p += pad((size_t)NE * 4);
    // pairs (NBKT*CAP*4 = 14.45 MB) aliases gbf (8 MB): pairs dead after binB,
    // gbf written by h afterwards.
    unsigned* pairs = (unsigned*)p;
    unsigned short* gbf = (unsigned short*)p;
    p += pad((size_t)NBKT * CAP * 4);
    unsigned short* wbf = (unsigned short*)p;   // 147456 B

    hipMemsetAsync(gcur, 0, (size_t)NBKT * 4, stream);

    wpack_kernel<<<(12 * 3 * 2 * 64 * 8 + 255) / 256, 256, 0, stream>>>(W, wbf);
    binA_kernel<<<ABLK, 256, 0, stream>>>(row, col, gcur, pairs);
    bscan_kernel<<<1, 256, 0, stream>>>(gcur, bbase);
    binB_kernel<<<NBKT, 1024, 0, stream>>>(gcur, bbase, pairs, ebuf, offs);
    h_kernel<<<(NN + 63) / 64, 256, 0, stream>>>(xE, xH, xS, wbf, offs, gbf);
    gather_kernel<<<(NN * 5 + 255) / 256, 256, 0, stream>>>(offs, ebuf, gbf, out);
}